// Round 3
// baseline (147.837 us; speedup 1.0000x reference)
//
#include <hip/hip_runtime.h>

// EmbeddingDistance: out[b] = 1 - dot(mean_i norm(x1[b,i,:]), mean_j norm(x2[b,j,:]))
// x1, x2: (16, 4096, 256) fp32, L3-resident on replays.
// R2: 2 rows/wave (32-lane halves) + DPP reduction -> 12x fewer LDS-pipe ops.

constexpr int D = 256;            // embedding dim
constexpr int S = 4096;           // segments (rows) per batch
constexpr int B = 16;             // batches
constexpr int BLOCKS_PER_SEQ = 64;
constexpr int WAVES_PER_BLOCK = 4;              // 256 threads
constexpr int WAVES_PER_SEQ  = BLOCKS_PER_SEQ * WAVES_PER_BLOCK;   // 256
constexpr int PAIRS_PER_WAVE = (S / 2) / WAVES_PER_SEQ;            // 8 row-pairs
constexpr int NSEQ  = 2 * B;                                       // 32
constexpr int NBLK1 = NSEQ * BLOCKS_PER_SEQ;                       // 2048
constexpr float EPS2 = 1e-16f;

// v_add_f32 with a DPP-permuted copy of x (VALU pipe, no LDS traffic).
template <int CTRL>
__device__ __forceinline__ float dpp_add(float x) {
    int xi = __builtin_bit_cast(int, x);
    int yi = __builtin_amdgcn_update_dpp(0, xi, CTRL, 0xf, 0xf, true);
    return x + __builtin_bit_cast(float, yi);
}

// Sum across each 32-lane half; every lane ends with its half's total.
// 4 DPP adds + 1 ds_swizzle (xor16 within the 32-group).
__device__ __forceinline__ float half_reduce(float x) {
    x = dpp_add<0xB1>(x);    // quad_perm [1,0,3,2]  : xor 1
    x = dpp_add<0x4E>(x);    // quad_perm [2,3,0,1]  : xor 2
    x = dpp_add<0x141>(x);   // row_half_mirror      : cross quads within 8
    x = dpp_add<0x140>(x);   // row_mirror           : cross 8-groups within 16
    int xi = __builtin_bit_cast(int, x);
    int yi = __builtin_amdgcn_ds_swizzle(xi, 0x401F);  // xor 16 within 32
    return x + __builtin_bit_cast(float, yi);
}

// ---- Kernel 1: one wave handles 2 rows at a time (lanes 0-31 -> even row,
// lanes 32-63 -> odd row; lane owns 8 floats of its row).  All 16 row-loads
// hoisted for MLP.  Block LDS reduction, then partial-store (or atomic).
template <bool USE_PARTIALS>
__global__ __launch_bounds__(256) void row_norm_sum_kernel(
    const float* __restrict__ x1, const float* __restrict__ x2,
    float* __restrict__ sums /* USE_PARTIALS ? [NBLK1][D] : [NSEQ][D] */)
{
    const int seq  = blockIdx.x / BLOCKS_PER_SEQ;       // 0..31
    const int blk  = blockIdx.x % BLOCKS_PER_SEQ;       // 0..63
    const int w    = threadIdx.x >> 6;                  // 0..3
    const int lane = threadIdx.x & 63;
    const int half = lane >> 5;                         // 0: even row, 1: odd
    const int l    = lane & 31;
    const int wv   = blk * WAVES_PER_BLOCK + w;         // 0..255 within seq

    const int batch = seq >> 1;
    const float* __restrict__ src = (seq & 1) ? x2 : x1;
    // lane's base: row (2*wv + half), dims [4l, 4l+4) and [128+4l, 128+4l+4)
    const float* base = src + (size_t)batch * S * D
                            + (size_t)(2 * wv + half) * D + 4 * l;

    float4 vlo[PAIRS_PER_WAVE], vhi[PAIRS_PER_WAVE];
    #pragma unroll
    for (int p = 0; p < PAIRS_PER_WAVE; ++p) {
        const float* a = base + (size_t)p * (WAVES_PER_SEQ * 2 * D);
        vlo[p] = *(const float4*)a;
        vhi[p] = *(const float4*)(a + 128);
    }

    float4 acc_lo = make_float4(0.f, 0.f, 0.f, 0.f);
    float4 acc_hi = make_float4(0.f, 0.f, 0.f, 0.f);
    #pragma unroll
    for (int p = 0; p < PAIRS_PER_WAVE; ++p) {
        float ss = vlo[p].x * vlo[p].x + vlo[p].y * vlo[p].y
                 + vlo[p].z * vlo[p].z + vlo[p].w * vlo[p].w
                 + vhi[p].x * vhi[p].x + vhi[p].y * vhi[p].y
                 + vhi[p].z * vhi[p].z + vhi[p].w * vhi[p].w;
        ss = half_reduce(ss);                 // per-row sum-of-squares
        const float s = rsqrtf(fmaxf(ss, EPS2));
        acc_lo.x += vlo[p].x * s;  acc_lo.y += vlo[p].y * s;
        acc_lo.z += vlo[p].z * s;  acc_lo.w += vlo[p].w * s;
        acc_hi.x += vhi[p].x * s;  acc_hi.y += vhi[p].y * s;
        acc_hi.z += vhi[p].z * s;  acc_hi.w += vhi[p].w * s;
    }

    // Block reduction: 4 waves x 2 halves of 256-dim partials.
    __shared__ float red[WAVES_PER_BLOCK][2][D];        // 8 KB
    *(float4*)&red[w][half][4 * l]       = acc_lo;
    *(float4*)&red[w][half][128 + 4 * l] = acc_hi;
    __syncthreads();

    const int t = threadIdx.x;
    float val = 0.f;
    #pragma unroll
    for (int ww = 0; ww < WAVES_PER_BLOCK; ++ww)
        val += red[ww][0][t] + red[ww][1][t];
    if (USE_PARTIALS) {
        sums[(size_t)blockIdx.x * D + t] = val;
    } else {
        atomicAdd(&sums[(size_t)seq * D + t], val);
    }
}

// ---- Kernel 2 (partials path): per batch, reduce 64-block partials for both
// inputs, dot them, block-reduce, write 1 - dot/S^2.
__global__ __launch_bounds__(256) void finalize_partials_kernel(
    const float* __restrict__ partials, float* __restrict__ out)
{
    const int b = blockIdx.x;
    const int t = threadIdx.x;
    const int w = t >> 6, lane = t & 63;

    const float* p1 = partials + ((size_t)(2 * b + 0) * BLOCKS_PER_SEQ) * D + t;
    const float* p2 = partials + ((size_t)(2 * b + 1) * BLOCKS_PER_SEQ) * D + t;
    float s1 = 0.f, s2 = 0.f;
    #pragma unroll 8
    for (int k = 0; k < BLOCKS_PER_SEQ; ++k) {
        s1 += p1[(size_t)k * D];
        s2 += p2[(size_t)k * D];
    }
    float d = s1 * s2;
    #pragma unroll
    for (int m = 1; m < 64; m <<= 1) d += __shfl_xor(d, m, 64);

    __shared__ float r[WAVES_PER_BLOCK];
    if (lane == 0) r[w] = d;
    __syncthreads();
    if (t == 0) {
        const float inv = 1.0f / ((float)S * (float)S);
        out[b] = 1.0f - (r[0] + r[1] + r[2] + r[3]) * inv;
    }
}

// ---- Kernel 2 (atomic fallback path): sums are already fully reduced.
__global__ __launch_bounds__(64) void finalize_kernel(
    const float* __restrict__ sums, float* __restrict__ out)
{
    const int b = blockIdx.x;
    const int lane = threadIdx.x;
    const float4 a = *(const float4*)(sums + (size_t)(2 * b + 0) * D + lane * 4);
    const float4 c = *(const float4*)(sums + (size_t)(2 * b + 1) * D + lane * 4);
    float d = a.x * c.x + a.y * c.y + a.z * c.z + a.w * c.w;
    #pragma unroll
    for (int m = 1; m < 64; m <<= 1) d += __shfl_xor(d, m, 64);
    if (lane == 0) {
        const float inv = 1.0f / ((float)S * (float)S);
        out[b] = 1.0f - d * inv;
    }
}

extern "C" void kernel_launch(void* const* d_in, const int* in_sizes, int n_in,
                              void* d_out, int out_size, void* d_ws, size_t ws_size,
                              hipStream_t stream) {
    const float* x1 = (const float*)d_in[0];
    const float* x2 = (const float*)d_in[1];
    float* out = (float*)d_out;
    float* ws = (float*)d_ws;

    const size_t partial_bytes = (size_t)NBLK1 * D * sizeof(float);   // 2 MB
    if (ws_size >= partial_bytes) {
        row_norm_sum_kernel<true><<<NBLK1, 256, 0, stream>>>(x1, x2, ws);
        finalize_partials_kernel<<<B, 256, 0, stream>>>(ws, out);
    } else {
        hipMemsetAsync(ws, 0, (size_t)NSEQ * D * sizeof(float), stream);
        row_norm_sum_kernel<false><<<NBLK1, 256, 0, stream>>>(x1, x2, ws);
        finalize_kernel<<<B, 64, 0, stream>>>(ws, out);
    }
}